// Round 12
// baseline (7128.739 us; speedup 1.0000x reference)
//
#include <hip/hip_runtime.h>
#include <math.h>

namespace {

constexpr int TPB  = 512;
constexpr int NB   = 256;   // batch
constexpr int NT   = 1000;  // time steps
constexpr int NX   = 64;    // state dim
constexpr int NS   = 4;     // control dim
constexpr int DIN  = 68;    // NX + NS
constexpr int HF   = 256;
constexpr int HG   = 128;
constexpr float DTC   = 0.01f;
constexpr float SIGMA = 0.1f;

constexpr int HPAD  = 288;  // padded h storage: idx + (idx>>5)*4
constexpr int CH    = 68;   // dW/out chunk row stride
constexpr int WG1LD = 133;  // s_wg1 row stride (odd -> 2-way conflicts, free)
constexpr int WG2LD = 136;  // s_wg2t row stride (16B-aligned rows)

typedef float v2f __attribute__((ext_vector_type(2)));

__device__ __forceinline__ int pmap(int i){ return i + ((i>>5)<<2); }

template<int CTRL>
__device__ __forceinline__ float dpp_add(float x){
    int y = __builtin_amdgcn_update_dpp(0, __float_as_int(x), CTRL, 0xF, 0xF, true);
    return x + __int_as_float(y);
}
// sum over lanes t^1, t^2 — quad_perm DPP (VALU pipe)
__device__ __forceinline__ float quad_sum(float x){
    x = dpp_add<0xB1>(x);   // quad_perm [1,0,3,2] : xor 1
    x = dpp_add<0x4E>(x);   // quad_perm [2,3,0,1] : xor 2
    return x;
}
// oct group = lane bits {0,1,3}: + xor8 via row_ror:8 — all DPP
__device__ __forceinline__ float oct_sum(float x){
    x = quad_sum(x);
    x = dpp_add<0x128>(x);  // row_ror:8 : lane l <-> l^8 within 16-lane row
    return x;
}

__device__ __forceinline__ float tanh_fast(float x){
    float e = __expf(2.0f*x);
    float r = __builtin_amdgcn_rcpf(e + 1.0f);
    return __builtin_fmaf(-2.0f, r, 1.0f);
}
__device__ __forceinline__ float softplus_f(float x){
    return fmaxf(x,0.0f) + __logf(1.0f + __expf(-fabsf(x)));
}

__device__ __forceinline__ v2f pkfma(v2f a, v2f b, v2f c){
    return __builtin_elementwise_fma(a, b, c);   // v_pk_fma_f32: 2 FMA / issue
}

// One workgroup = one batch element for all 1000 steps. 12 barriers/step.
// r11 finding: per-step asm keepalive on the F-weights prevents the compiler
// from sinking weight loads into the loop (the L2-refetch wall) -> 5.07 ms,
// VALUBusy 77% (issue-bound). This round: scalar v_fma -> v_pk_fma_f32
// (2 FMA/issue) in all three F phases; keepalive retained on packed arrays.
__global__ __launch_bounds__(TPB, 1) void sde_rk4_kernel(
    const float* __restrict__ gIn, const float* __restrict__ gNz,
    const float* __restrict__ Wf1, const float* __restrict__ bf1,
    const float* __restrict__ Wf2, const float* __restrict__ bf2,
    const float* __restrict__ Wf3, const float* __restrict__ bf3,
    const float* __restrict__ Wg1, const float* __restrict__ bg1,
    const float* __restrict__ Wg2, const float* __restrict__ bg2,
    float* __restrict__ gOut)
{
    const int b = blockIdx.x;
    const int t = threadIdx.x;

    __shared__ __align__(16) float s_z[72];        // [X(64), u(4), pad]
    __shared__ __align__(16) float s_h1[HPAD];
    __shared__ __align__(16) float s_h2[HPAD];
    __shared__ __align__(16) float s_hg[HG];
    __shared__ __align__(16) float s_uall[4008];   // u[step][4] (+pad)
    __shared__ __align__(16) float s_dwc[NX*CH];   // dW chunk [x][64]
    __shared__ __align__(16) float s_out[NX*CH];   // out buffer [x][64]
    __shared__ __align__(16) float s_wg1[72*WG1LD];   // [k][c]
    __shared__ __align__(16) float s_wg2t[NX*WG2LD];  // [c][k] transposed

    // ---- thread roles (identical to r11) ----
    const int q2 = t & 3;                                   // quad slice id
    const int s8 = (t & 3) | (((t >> 3) & 1) << 2);         // oct slice (bits t0,t1,t3)
    const int gA = t >> 2;          const int cA0 = 2*gA;   // L1 col group (128)
    const int k0A = 16*q2;          const int lenA = (q2==3)?20:16;
    const int gB = ((t>>2)&1) | ((t>>4)<<1);                // oct col group (64)
    const int cB0 = 4*gB;           const int k0B = 32*s8;  // L2
    const int cC  = gB;             const int k0C = 32*s8;  // L3
    const int k0H = 16*s8;                                  // G2 k-slice
    const int cG  = gA;             const int k0G = 17*q2;  // G1 (17-row slices)
    const bool oct0  = (s8 == 0);
    const bool quad0 = (q2 == 0);
    const int rD = t>>3, j0D = (t&7)*8;                     // chunk roles

    // ---- F-weights -> packed registers (zero-padded slices, 200 floats) ----
    v2f wf1r[20];                              // pairs across output cols
#pragma unroll
    for (int k=0;k<20;++k){
        v2f w = {0.f, 0.f};
        if (k < lenA) w = *(const v2f*)&Wf1[(k0A+k)*HF + cA0];
        wf1r[k] = w;
    }
    v2f wf2r[32][2];                           // [k][colpair]
#pragma unroll
    for (int k=0;k<32;++k){
        const float4 wv = *(const float4*)&Wf2[(size_t)(k0B+k)*HF + cB0];
        wf2r[k][0] = (v2f){wv.x, wv.y};
        wf2r[k][1] = (v2f){wv.z, wv.w};
    }
    v2f wf3p[16];                              // pairs along k
#pragma unroll
    for (int j=0;j<16;++j)
        wf3p[j] = (v2f){ Wf3[(k0C+2*j)*NX + cC], Wf3[(k0C+2*j+1)*NX + cC] };

    const float2 bf1v = *(const float2*)&bf1[cA0];
    const float4 bf2v = *(const float4*)&bf2[cB0];
    const float bf3c = bf3[cC];
    const float bg1c = bg1[cG];
    const float bg2c = bg2[cC];

    const float sq = sqrtf(DTC);
    const float* inB = gIn + (size_t)b*DIN*NT;
    const float* nzB = gNz + (size_t)b*NX*NT;
    float*      outB = gOut + (size_t)b*NX*NT;

    // ---- G-weights -> LDS; u sequence -> LDS; initial state ----
    for (int i=t;i<72*HG;i+=TPB){
        const int k=i>>7, c=i&(HG-1);
        s_wg1[k*WG1LD+c] = (k<DIN) ? Wg1[k*HG+c] : 0.f;
    }
    for (int i=t;i<HG*NX;i+=TPB){
        const int k=i>>6, c=i&(NX-1);
        s_wg2t[c*WG2LD+k] = Wg2[i];
    }
    for (int i=t;i<NS*NT; i+=TPB) s_uall[i] = inB[(i&3)*NT + (i>>2)];
    if (t<8)            s_uall[NS*NT+t] = 0.f;
    if (t>=68 && t<72)  s_z[t] = 0.f;
    if (t<4)            s_z[64+t] = inB[t*NT];
    float X = inB[(size_t)(NS+cC)*NT];   // replicated across oct group
    float kacc = 0.f, gc = 0.f;
    if (oct0) s_z[cC] = X;
    __syncthreads();

    // ---------- phases ----------
    auto phaseA = [&](bool withG){
        v2f acc0 = {0.f,0.f}, acc1 = {0.f,0.f};
#pragma unroll
        for (int q=0;q<5;++q){                 // weights zero-padded beyond lenA
            const float4 zv = *(const float4*)&s_z[k0A + 4*q];
            acc0 = pkfma((v2f){zv.x,zv.x}, wf1r[4*q+0], acc0);
            acc1 = pkfma((v2f){zv.y,zv.y}, wf1r[4*q+1], acc1);
            acc0 = pkfma((v2f){zv.z,zv.z}, wf1r[4*q+2], acc0);
            acc1 = pkfma((v2f){zv.w,zv.w}, wf1r[4*q+3], acc1);
        }
        const v2f accs = acc0 + acc1;
        const float r0 = quad_sum(accs[0]);
        const float r1 = quad_sum(accs[1]);
        float2 hv = { tanh_fast(r0 + bf1v.x), tanh_fast(r1 + bf1v.y) };
        if (quad0) *(float2*)&s_h1[pmap(cA0)] = hv;
        if (withG){
            float g0=0.f, g1=0.f;
#pragma unroll
            for (int i=0;i<17;++i){            // 4 slices x 17 rows = 68 exact
                const float zk = s_z[k0G+i];
                const float wk = s_wg1[(k0G+i)*WG1LD + cG];
                if (i & 1) g1 = fmaf(zk, wk, g1); else g0 = fmaf(zk, wk, g0);
            }
            const float agr = quad_sum(g0 + g1);
            if (quad0) s_hg[cG] = tanh_fast(agr + bg1c);
        }
        __syncthreads();
    };

    auto phaseB = [&](bool withG){
        v2f A0={0.f,0.f}, B0={0.f,0.f};        // cols (cB0, cB0+1)
        v2f A1={0.f,0.f}, B1={0.f,0.f};        // cols (cB0+2, cB0+3)
        const float* h1p = &s_h1[36*s8];       // pmap(32*s8 + j) = 36*s8 + j
#pragma unroll
        for (int q=0;q<8;++q){
            const float4 hv = *(const float4*)&h1p[4*q];
            A0 = pkfma((v2f){hv.x,hv.x}, wf2r[4*q+0][0], A0);
            A1 = pkfma((v2f){hv.x,hv.x}, wf2r[4*q+0][1], A1);
            B0 = pkfma((v2f){hv.y,hv.y}, wf2r[4*q+1][0], B0);
            B1 = pkfma((v2f){hv.y,hv.y}, wf2r[4*q+1][1], B1);
            A0 = pkfma((v2f){hv.z,hv.z}, wf2r[4*q+2][0], A0);
            A1 = pkfma((v2f){hv.z,hv.z}, wf2r[4*q+2][1], A1);
            B0 = pkfma((v2f){hv.w,hv.w}, wf2r[4*q+3][0], B0);
            B1 = pkfma((v2f){hv.w,hv.w}, wf2r[4*q+3][1], B1);
        }
        const v2f S0 = A0 + B0, S1 = A1 + B1;
        const float d0 = oct_sum(S0[0]);
        const float d1 = oct_sum(S0[1]);
        const float d2 = oct_sum(S1[0]);
        const float d3 = oct_sum(S1[1]);
        if (withG){
            float g0=0.f, g1=0.f;
            const float* wt = &s_wg2t[cC*WG2LD + k0H];
            const float* hp = &s_hg[k0H];
#pragma unroll
            for (int q=0;q<4;++q){
                const float4 wv = *(const float4*)&wt[4*q];
                const float4 hg = *(const float4*)&hp[4*q];
                g0 = fmaf(hg.x, wv.x, g0);  g1 = fmaf(hg.y, wv.y, g1);
                g0 = fmaf(hg.z, wv.z, g0);  g1 = fmaf(hg.w, wv.w, g1);
            }
            const float gq = oct_sum(g0 + g1);
            gc = SIGMA*softplus_f(gq + bg2c);  // replicated across oct
        }
        float4 hv;
        hv.x = tanh_fast(d0 + bf2v.x);
        hv.y = tanh_fast(d1 + bf2v.y);
        hv.z = tanh_fast(d2 + bf2v.z);
        hv.w = tanh_fast(d3 + bf2v.w);
        if (oct0) *(float4*)&s_h2[pmap(cB0)] = hv;
        __syncthreads();
    };

    auto phaseC = [&](int ev, int st){
        v2f e0={0.f,0.f}, e1={0.f,0.f};
        const float* h2p = &s_h2[36*s8];
#pragma unroll
        for (int q=0;q<8;++q){
            const float4 hv = *(const float4*)&h2p[4*q];
            e0 = pkfma((v2f){hv.x,hv.y}, wf3p[2*q+0], e0);
            e1 = pkfma((v2f){hv.z,hv.w}, wf3p[2*q+1], e1);
        }
        const v2f es = e0 + e1;
        const float kv = oct_sum(es[0] + es[1]) + bf3c; // replicated across oct
        if (ev==0)      kacc = kv;
        else if (ev==3) kacc += kv;
        else            kacc += 2.0f*kv;
        if (ev<3){
            if (oct0) s_z[cC] = fmaf((ev==2)?DTC:0.5f*DTC, kv, X);
        } else {
            const int jj = st & 63;
            const float dw = s_dwc[cC*CH + jj];        // broadcast within oct
            X = X + (DTC/6.0f)*kacc + gc*dw;           // replicated update
            if (oct0){
                s_z[cC] = X;
                s_out[cC*CH + jj] = X;
                if (cC < NS) s_z[64+cC] = s_uall[(st+1)*4 + cC];
            }
        }
        __syncthreads();
    };

    // ---------- main loop ----------
#pragma unroll 1
    for (int st=0; st<NT; ++st){
        // KEEPALIVE: opaquely redefine every F-weight register each step.
        // No instructions emitted; forbids sinking the weight loads back into
        // the loop (the r10 L2-refetch wall; removing this cost 2.8 ms).
#pragma unroll
        for (int k=0;k<20;++k)
            asm volatile("" : "+v"(wf1r[k]));
#pragma unroll
        for (int k=0;k<32;++k)
            asm volatile("" : "+v"(wf2r[k][0]), "+v"(wf2r[k][1]));
#pragma unroll
        for (int j=0;j<16;++j)
            asm volatile("" : "+v"(wf3p[j]));

        if ((st & 63) == 0){
            if (st + 64 <= NT){
                const float4 v0 = *(const float4*)&nzB[(size_t)rD*NT + st + j0D];
                const float4 v1 = *(const float4*)&nzB[(size_t)rD*NT + st + j0D + 4];
                float* d = &s_dwc[rD*CH + j0D];
                d[0]=v0.x*sq; d[1]=v0.y*sq; d[2]=v0.z*sq; d[3]=v0.w*sq;
                d[4]=v1.x*sq; d[5]=v1.y*sq; d[6]=v1.z*sq; d[7]=v1.w*sq;
            } else {
#pragma unroll
                for (int e=0;e<8;++e){
                    const int j = j0D + e;
                    const float v = (st + j < NT) ? nzB[(size_t)rD*NT + st + j] : 0.f;
                    s_dwc[rD*CH + j] = v*sq;
                }
            }
        }

        phaseA(true);  phaseB(true);  phaseC(0, st);
#pragma unroll
        for (int ev=1; ev<4; ++ev){
            phaseA(false); phaseB(false); phaseC(ev, st);
        }

        const int jj = st & 63;
        if (jj == 63 || st == NT-1){
            const int st0 = st & ~63;
            const int cnt = st - st0 + 1;
            if (cnt == 64){
                const float4 w0 = *(const float4*)&s_out[rD*CH + j0D];
                const float4 w1 = *(const float4*)&s_out[rD*CH + j0D + 4];
                *(float4*)&outB[(size_t)rD*NT + st0 + j0D]     = w0;
                *(float4*)&outB[(size_t)rD*NT + st0 + j0D + 4] = w1;
            } else {
#pragma unroll
                for (int e=0;e<8;++e){
                    const int j = j0D + e;
                    if (j < cnt) outB[(size_t)rD*NT + st0 + j] = s_out[rD*CH + j];
                }
            }
        }
    }
}

} // namespace

extern "C" void kernel_launch(void* const* d_in, const int* in_sizes, int n_in,
                              void* d_out, int out_size, void* d_ws, size_t ws_size,
                              hipStream_t stream)
{
    const float* Inputs = (const float*)d_in[0];
    const float* noise  = (const float*)d_in[1];
    // d_in[2] = t0 (unused)
    const float* Wf1 = (const float*)d_in[3];
    const float* bf1 = (const float*)d_in[4];
    const float* Wf2 = (const float*)d_in[5];
    const float* bf2 = (const float*)d_in[6];
    const float* Wf3 = (const float*)d_in[7];
    const float* bf3 = (const float*)d_in[8];
    const float* Wg1 = (const float*)d_in[9];
    const float* bg1 = (const float*)d_in[10];
    const float* Wg2 = (const float*)d_in[11];
    const float* bg2 = (const float*)d_in[12];
    float* out = (float*)d_out;

    sde_rk4_kernel<<<dim3(NB), dim3(TPB), 0, stream>>>(
        Inputs, noise, Wf1, bf1, Wf2, bf2, Wf3, bf3, Wg1, bg1, Wg2, bg2, out);
}

// Round 13
// 6544.182 us; speedup vs baseline: 1.0893x; 1.0893x over previous
//
#include <hip/hip_runtime.h>
#include <math.h>

namespace {

constexpr int TPB  = 512;
constexpr int NB   = 256;   // batch
constexpr int NT   = 1000;  // time steps
constexpr int NX   = 64;    // state dim
constexpr int NS   = 4;     // control dim
constexpr int DIN  = 68;    // NX + NS
constexpr int HF   = 256;
constexpr int HG   = 128;
constexpr float DTC   = 0.01f;
constexpr float SIGMA = 0.1f;

constexpr int HPAD  = 288;  // padded h storage: idx + (idx>>5)*4
constexpr int CH    = 68;   // dW/out chunk row stride
constexpr int WG1LD = 133;  // s_wg1 row stride (odd -> 2-way conflicts, free)
constexpr int WG2LD = 136;  // s_wg2t row stride (16B-aligned rows)

typedef float v2f __attribute__((ext_vector_type(2)));

__device__ __forceinline__ int pmap(int i){ return i + ((i>>5)<<2); }

template<int CTRL>
__device__ __forceinline__ float dpp_add(float x){
    int y = __builtin_amdgcn_update_dpp(0, __float_as_int(x), CTRL, 0xF, 0xF, true);
    return x + __int_as_float(y);
}
// sum over lanes t^1, t^2 — quad_perm DPP (VALU pipe)
__device__ __forceinline__ float quad_sum(float x){
    x = dpp_add<0xB1>(x);   // quad_perm [1,0,3,2] : xor 1
    x = dpp_add<0x4E>(x);   // quad_perm [2,3,0,1] : xor 2
    return x;
}
// oct group = lane bits {0,1,3}: + xor8 via row_ror:8 — all DPP
__device__ __forceinline__ float oct_sum(float x){
    x = quad_sum(x);
    x = dpp_add<0x128>(x);  // row_ror:8 : lane l <-> l^8 within 16-lane row
    return x;
}

__device__ __forceinline__ float tanh_fast(float x){
    float e = __expf(2.0f*x);
    float r = __builtin_amdgcn_rcpf(e + 1.0f);
    return __builtin_fmaf(-2.0f, r, 1.0f);
}
__device__ __forceinline__ float softplus_f(float x){
    return fmaxf(x,0.0f) + __logf(1.0f + __expf(-fabsf(x)));
}

__device__ __forceinline__ v2f pkfma(v2f a, v2f b, v2f c){
    return __builtin_elementwise_fma(a, b, c);   // v_pk_fma_f32: 2 FMA / issue
}

// One workgroup = one batch element for all 1000 steps. 12 barriers/step.
// r11: keepalive -> weights truly register-resident -> 5.07 ms, VALUBusy 77%.
// r12 lesson: column-pair packing spilled (broadcast temporaries; WRITE +24MB).
// This round: K-pair packing — both pkfma operands are NATURAL register pairs
// ((hv.x,hv.y) from b128 reads; {W[k],W[k+1]} weight pairs) — no broadcasts,
// no movs. F-FMA issue halves (800 -> 400/step).
__global__ __launch_bounds__(TPB, 1) void sde_rk4_kernel(
    const float* __restrict__ gIn, const float* __restrict__ gNz,
    const float* __restrict__ Wf1, const float* __restrict__ bf1,
    const float* __restrict__ Wf2, const float* __restrict__ bf2,
    const float* __restrict__ Wf3, const float* __restrict__ bf3,
    const float* __restrict__ Wg1, const float* __restrict__ bg1,
    const float* __restrict__ Wg2, const float* __restrict__ bg2,
    float* __restrict__ gOut)
{
    const int b = blockIdx.x;
    const int t = threadIdx.x;

    __shared__ __align__(16) float s_z[72];        // [X(64), u(4), pad]
    __shared__ __align__(16) float s_h1[HPAD];
    __shared__ __align__(16) float s_h2[HPAD];
    __shared__ __align__(16) float s_hg[HG];
    __shared__ __align__(16) float s_uall[4008];   // u[step][4] (+pad)
    __shared__ __align__(16) float s_dwc[NX*CH];   // dW chunk [x][64]
    __shared__ __align__(16) float s_out[NX*CH];   // out buffer [x][64]
    __shared__ __align__(16) float s_wg1[72*WG1LD];   // [k][c]
    __shared__ __align__(16) float s_wg2t[NX*WG2LD];  // [c][k] transposed

    // ---- thread roles (identical to r11) ----
    const int q2 = t & 3;                                   // quad slice id
    const int s8 = (t & 3) | (((t >> 3) & 1) << 2);         // oct slice (bits t0,t1,t3)
    const int gA = t >> 2;          const int cA0 = 2*gA;   // L1 col group (128)
    const int k0A = 16*q2;          const int lenA = (q2==3)?20:16;
    const int gB = ((t>>2)&1) | ((t>>4)<<1);                // oct col group (64)
    const int cB0 = 4*gB;           const int k0B = 32*s8;  // L2
    const int cC  = gB;             const int k0C = 32*s8;  // L3
    const int k0H = 16*s8;                                  // G2 k-slice
    const int cG  = gA;             const int k0G = 17*q2;  // G1 (17-row slices)
    const bool oct0  = (s8 == 0);
    const bool quad0 = (q2 == 0);
    const int rD = t>>3, j0D = (t&7)*8;                     // chunk roles

    // ---- F-weights -> K-PAIR packed registers (zero-padded, 200 floats) ----
    v2f wf1ka[10], wf1kb[10];      // {W[2k],W[2k+1]} for cols cA0, cA0+1
#pragma unroll
    for (int k=0;k<10;++k){
        v2f a = {0.f,0.f}, bb = {0.f,0.f};
        if (2*k < lenA){           // lenA even (16 or 20)
            a  = (v2f){ Wf1[(k0A+2*k)*HF + cA0],     Wf1[(k0A+2*k+1)*HF + cA0]     };
            bb = (v2f){ Wf1[(k0A+2*k)*HF + cA0 + 1], Wf1[(k0A+2*k+1)*HF + cA0 + 1] };
        }
        wf1ka[k] = a; wf1kb[k] = bb;
    }
    v2f wf2kp[16][4];              // [kpair][col j]: {W[2k][j], W[2k+1][j]}
#pragma unroll
    for (int kp=0;kp<16;++kp){
        const float4 w0 = *(const float4*)&Wf2[(size_t)(k0B+2*kp)*HF + cB0];
        const float4 w1 = *(const float4*)&Wf2[(size_t)(k0B+2*kp+1)*HF + cB0];
        wf2kp[kp][0] = (v2f){w0.x, w1.x};
        wf2kp[kp][1] = (v2f){w0.y, w1.y};
        wf2kp[kp][2] = (v2f){w0.z, w1.z};
        wf2kp[kp][3] = (v2f){w0.w, w1.w};
    }
    v2f wf3p[16];                  // k-pairs for col cC
#pragma unroll
    for (int j=0;j<16;++j)
        wf3p[j] = (v2f){ Wf3[(k0C+2*j)*NX + cC], Wf3[(k0C+2*j+1)*NX + cC] };

    const float2 bf1v = *(const float2*)&bf1[cA0];
    const float4 bf2v = *(const float4*)&bf2[cB0];
    const float bf3c = bf3[cC];
    const float bg1c = bg1[cG];
    const float bg2c = bg2[cC];

    const float sq = sqrtf(DTC);
    const float* inB = gIn + (size_t)b*DIN*NT;
    const float* nzB = gNz + (size_t)b*NX*NT;
    float*      outB = gOut + (size_t)b*NX*NT;

    // ---- G-weights -> LDS; u sequence -> LDS; initial state ----
    for (int i=t;i<72*HG;i+=TPB){
        const int k=i>>7, c=i&(HG-1);
        s_wg1[k*WG1LD+c] = (k<DIN) ? Wg1[k*HG+c] : 0.f;
    }
    for (int i=t;i<HG*NX;i+=TPB){
        const int k=i>>6, c=i&(NX-1);
        s_wg2t[c*WG2LD+k] = Wg2[i];
    }
    for (int i=t;i<NS*NT; i+=TPB) s_uall[i] = inB[(i&3)*NT + (i>>2)];
    if (t<8)            s_uall[NS*NT+t] = 0.f;
    if (t>=68 && t<72)  s_z[t] = 0.f;
    if (t<4)            s_z[64+t] = inB[t*NT];
    float X = inB[(size_t)(NS+cC)*NT];   // replicated across oct group
    float kacc = 0.f, gc = 0.f;
    if (oct0) s_z[cC] = X;
    __syncthreads();

    // ---------- phases ----------
    auto phaseA = [&](bool withG){
        v2f accA = {0.f,0.f}, accB = {0.f,0.f};
#pragma unroll
        for (int q=0;q<5;++q){                 // weights zero-padded beyond lenA
            const float4 zv = *(const float4*)&s_z[k0A + 4*q];
            const v2f z01 = (v2f){zv.x, zv.y};
            const v2f z23 = (v2f){zv.z, zv.w};
            accA = pkfma(z01, wf1ka[2*q+0], accA);
            accB = pkfma(z01, wf1kb[2*q+0], accB);
            accA = pkfma(z23, wf1ka[2*q+1], accA);
            accB = pkfma(z23, wf1kb[2*q+1], accB);
        }
        const float r0 = quad_sum(accA[0] + accA[1]);
        const float r1 = quad_sum(accB[0] + accB[1]);
        float2 hv = { tanh_fast(r0 + bf1v.x), tanh_fast(r1 + bf1v.y) };
        if (quad0) *(float2*)&s_h1[pmap(cA0)] = hv;
        if (withG){
            float g0=0.f, g1=0.f;
#pragma unroll
            for (int i=0;i<17;++i){            // 4 slices x 17 rows = 68 exact
                const float zk = s_z[k0G+i];
                const float wk = s_wg1[(k0G+i)*WG1LD + cG];
                if (i & 1) g1 = fmaf(zk, wk, g1); else g0 = fmaf(zk, wk, g0);
            }
            const float agr = quad_sum(g0 + g1);
            if (quad0) s_hg[cG] = tanh_fast(agr + bg1c);
        }
        __syncthreads();
    };

    auto phaseB = [&](bool withG){
        v2f a0={0.f,0.f}, a1={0.f,0.f}, a2={0.f,0.f}, a3={0.f,0.f};
        const float* h1p = &s_h1[36*s8];       // pmap(32*s8 + j) = 36*s8 + j
#pragma unroll
        for (int q=0;q<8;++q){
            const float4 hv = *(const float4*)&h1p[4*q];
            const v2f h01 = (v2f){hv.x, hv.y};
            const v2f h23 = (v2f){hv.z, hv.w};
            a0 = pkfma(h01, wf2kp[2*q+0][0], a0);
            a1 = pkfma(h01, wf2kp[2*q+0][1], a1);
            a2 = pkfma(h01, wf2kp[2*q+0][2], a2);
            a3 = pkfma(h01, wf2kp[2*q+0][3], a3);
            a0 = pkfma(h23, wf2kp[2*q+1][0], a0);
            a1 = pkfma(h23, wf2kp[2*q+1][1], a1);
            a2 = pkfma(h23, wf2kp[2*q+1][2], a2);
            a3 = pkfma(h23, wf2kp[2*q+1][3], a3);
        }
        const float d0 = oct_sum(a0[0] + a0[1]);
        const float d1 = oct_sum(a1[0] + a1[1]);
        const float d2 = oct_sum(a2[0] + a2[1]);
        const float d3 = oct_sum(a3[0] + a3[1]);
        if (withG){
            float g0=0.f, g1=0.f;
            const float* wt = &s_wg2t[cC*WG2LD + k0H];
            const float* hp = &s_hg[k0H];
#pragma unroll
            for (int q=0;q<4;++q){
                const float4 wv = *(const float4*)&wt[4*q];
                const float4 hg = *(const float4*)&hp[4*q];
                g0 = fmaf(hg.x, wv.x, g0);  g1 = fmaf(hg.y, wv.y, g1);
                g0 = fmaf(hg.z, wv.z, g0);  g1 = fmaf(hg.w, wv.w, g1);
            }
            const float gq = oct_sum(g0 + g1);
            gc = SIGMA*softplus_f(gq + bg2c);  // replicated across oct
        }
        float4 hv;
        hv.x = tanh_fast(d0 + bf2v.x);
        hv.y = tanh_fast(d1 + bf2v.y);
        hv.z = tanh_fast(d2 + bf2v.z);
        hv.w = tanh_fast(d3 + bf2v.w);
        if (oct0) *(float4*)&s_h2[pmap(cB0)] = hv;
        __syncthreads();
    };

    auto phaseC = [&](int ev, int st){
        v2f e0={0.f,0.f}, e1={0.f,0.f};
        const float* h2p = &s_h2[36*s8];
#pragma unroll
        for (int q=0;q<8;++q){
            const float4 hv = *(const float4*)&h2p[4*q];
            e0 = pkfma((v2f){hv.x,hv.y}, wf3p[2*q+0], e0);
            e1 = pkfma((v2f){hv.z,hv.w}, wf3p[2*q+1], e1);
        }
        const v2f es = e0 + e1;
        const float kv = oct_sum(es[0] + es[1]) + bf3c; // replicated across oct
        if (ev==0)      kacc = kv;
        else if (ev==3) kacc += kv;
        else            kacc += 2.0f*kv;
        if (ev<3){
            if (oct0) s_z[cC] = fmaf((ev==2)?DTC:0.5f*DTC, kv, X);
        } else {
            const int jj = st & 63;
            const float dw = s_dwc[cC*CH + jj];        // broadcast within oct
            X = X + (DTC/6.0f)*kacc + gc*dw;           // replicated update
            if (oct0){
                s_z[cC] = X;
                s_out[cC*CH + jj] = X;
                if (cC < NS) s_z[64+cC] = s_uall[(st+1)*4 + cC];
            }
        }
        __syncthreads();
    };

    // ---------- main loop ----------
#pragma unroll 1
    for (int st=0; st<NT; ++st){
        // KEEPALIVE: opaquely redefine every F-weight register each step.
        // No instructions emitted; forbids sinking the weight loads back into
        // the loop (the r10 L2-refetch wall; removing this cost 2.8 ms).
#pragma unroll
        for (int k=0;k<10;++k)
            asm volatile("" : "+v"(wf1ka[k]), "+v"(wf1kb[k]));
#pragma unroll
        for (int kp=0;kp<16;++kp)
            asm volatile("" : "+v"(wf2kp[kp][0]), "+v"(wf2kp[kp][1]),
                              "+v"(wf2kp[kp][2]), "+v"(wf2kp[kp][3]));
#pragma unroll
        for (int j=0;j<16;++j)
            asm volatile("" : "+v"(wf3p[j]));

        if ((st & 63) == 0){
            if (st + 64 <= NT){
                const float4 v0 = *(const float4*)&nzB[(size_t)rD*NT + st + j0D];
                const float4 v1 = *(const float4*)&nzB[(size_t)rD*NT + st + j0D + 4];
                float* d = &s_dwc[rD*CH + j0D];
                d[0]=v0.x*sq; d[1]=v0.y*sq; d[2]=v0.z*sq; d[3]=v0.w*sq;
                d[4]=v1.x*sq; d[5]=v1.y*sq; d[6]=v1.z*sq; d[7]=v1.w*sq;
            } else {
#pragma unroll
                for (int e=0;e<8;++e){
                    const int j = j0D + e;
                    const float v = (st + j < NT) ? nzB[(size_t)rD*NT + st + j] : 0.f;
                    s_dwc[rD*CH + j] = v*sq;
                }
            }
        }

        phaseA(true);  phaseB(true);  phaseC(0, st);
#pragma unroll
        for (int ev=1; ev<4; ++ev){
            phaseA(false); phaseB(false); phaseC(ev, st);
        }

        const int jj = st & 63;
        if (jj == 63 || st == NT-1){
            const int st0 = st & ~63;
            const int cnt = st - st0 + 1;
            if (cnt == 64){
                const float4 w0 = *(const float4*)&s_out[rD*CH + j0D];
                const float4 w1 = *(const float4*)&s_out[rD*CH + j0D + 4];
                *(float4*)&outB[(size_t)rD*NT + st0 + j0D]     = w0;
                *(float4*)&outB[(size_t)rD*NT + st0 + j0D + 4] = w1;
            } else {
#pragma unroll
                for (int e=0;e<8;++e){
                    const int j = j0D + e;
                    if (j < cnt) outB[(size_t)rD*NT + st0 + j] = s_out[rD*CH + j];
                }
            }
        }
    }
}

} // namespace

extern "C" void kernel_launch(void* const* d_in, const int* in_sizes, int n_in,
                              void* d_out, int out_size, void* d_ws, size_t ws_size,
                              hipStream_t stream)
{
    const float* Inputs = (const float*)d_in[0];
    const float* noise  = (const float*)d_in[1];
    // d_in[2] = t0 (unused)
    const float* Wf1 = (const float*)d_in[3];
    const float* bf1 = (const float*)d_in[4];
    const float* Wf2 = (const float*)d_in[5];
    const float* bf2 = (const float*)d_in[6];
    const float* Wf3 = (const float*)d_in[7];
    const float* bf3 = (const float*)d_in[8];
    const float* Wg1 = (const float*)d_in[9];
    const float* bg1 = (const float*)d_in[10];
    const float* Wg2 = (const float*)d_in[11];
    const float* bg2 = (const float*)d_in[12];
    float* out = (float*)d_out;

    sde_rk4_kernel<<<dim3(NB), dim3(TPB), 0, stream>>>(
        Inputs, noise, Wf1, bf1, Wf2, bf2, Wf3, bf3, Wg1, bg1, Wg2, bg2, out);
}

// Round 14
// 4630.429 us; speedup vs baseline: 1.5395x; 1.4133x over previous
//
#include <hip/hip_runtime.h>
#include <math.h>

namespace {

constexpr int TPB  = 512;
constexpr int NB   = 256;   // batch
constexpr int NT   = 1000;  // time steps
constexpr int NX   = 64;    // state dim
constexpr int NS   = 4;     // control dim
constexpr int DIN  = 68;    // NX + NS
constexpr int HF   = 256;
constexpr int HG   = 128;
constexpr float DTC   = 0.01f;
constexpr float SIGMA = 0.1f;

constexpr int HPAD  = 288;  // padded h storage: idx + (idx>>5)*4
constexpr int CH    = 68;   // dW/out chunk row stride
constexpr int WG1P  = 84;   // s_wg1p row stride: 4x20-slot padded slices + pad
constexpr int WG2LD = 136;  // s_wg2t row stride (16B-aligned rows)

__device__ __forceinline__ int pmap(int i){ return i + ((i>>5)<<2); }

template<int CTRL>
__device__ __forceinline__ float dpp_add(float x){
    int y = __builtin_amdgcn_update_dpp(0, __float_as_int(x), CTRL, 0xF, 0xF, true);
    return x + __int_as_float(y);
}
// sum over lanes t^1, t^2 — quad_perm DPP (VALU pipe)
__device__ __forceinline__ float quad_sum(float x){
    x = dpp_add<0xB1>(x);   // quad_perm [1,0,3,2] : xor 1
    x = dpp_add<0x4E>(x);   // quad_perm [2,3,0,1] : xor 2
    return x;
}
// oct group = lane bits {0,1,3}: + xor8 via row_ror:8 — all DPP
__device__ __forceinline__ float oct_sum(float x){
    x = quad_sum(x);
    x = dpp_add<0x128>(x);  // row_ror:8 : lane l <-> l^8 within 16-lane row
    return x;
}

__device__ __forceinline__ float tanh_fast(float x){
    float e = __expf(2.0f*x);
    float r = __builtin_amdgcn_rcpf(e + 1.0f);
    return __builtin_fmaf(-2.0f, r, 1.0f);
}
__device__ __forceinline__ float softplus_f(float x){
    return fmaxf(x,0.0f) + __logf(1.0f + __expf(-fabsf(x)));
}

// One workgroup = one batch element for all 1000 steps. 12 barriers/step.
// r11 base (scalar register weights + per-step keepalive = 5.07ms, 77% busy).
// r12/r13 lesson: v2f weight packing spills — stay scalar.
// This round: (1) merged-tanh — one tanh issue per phase via per-lane cndmask
// input select + per-lane write pointer (22 -> ~9 tanh issues/step);
// (2) G1 via transposed zero-padded LDS tiles sharing phaseA's z-quad reads.
__global__ __launch_bounds__(TPB, 1) void sde_rk4_kernel(
    const float* __restrict__ gIn, const float* __restrict__ gNz,
    const float* __restrict__ Wf1, const float* __restrict__ bf1,
    const float* __restrict__ Wf2, const float* __restrict__ bf2,
    const float* __restrict__ Wf3, const float* __restrict__ bf3,
    const float* __restrict__ Wg1, const float* __restrict__ bg1,
    const float* __restrict__ Wg2, const float* __restrict__ bg2,
    float* __restrict__ gOut)
{
    const int b = blockIdx.x;
    const int t = threadIdx.x;

    __shared__ __align__(16) float s_z[72];        // [X(64), u(4), pad=0]
    __shared__ __align__(16) float s_h1[HPAD];
    __shared__ __align__(16) float s_h2[HPAD];
    __shared__ __align__(16) float s_hg[HG];
    __shared__ __align__(16) float s_uall[4008];   // u[step][4] (+pad)
    __shared__ __align__(16) float s_dwc[NX*CH];   // dW chunk [x][64]
    __shared__ __align__(16) float s_out[NX*CH];   // out buffer [x][64]
    __shared__ __align__(16) float s_wg1p[HG*WG1P];   // [c][4 slices x 20 pad]
    __shared__ __align__(16) float s_wg2t[NX*WG2LD];  // [c][k] transposed

    // ---- thread roles (identical to r11) ----
    const int q2 = t & 3;                                   // quad slice id
    const int s8 = (t & 3) | (((t >> 3) & 1) << 2);         // oct slice (bits t0,t1,t3)
    const int gA = t >> 2;          const int cA0 = 2*gA;   // L1 col group (128)
    const int k0A = 16*q2;          const int lenA = (q2==3)?20:16;
    const int gB = ((t>>2)&1) | ((t>>4)<<1);                // oct col group (64)
    const int cB0 = 4*gB;           const int k0B = 32*s8;  // L2
    const int cC  = gB;             const int k0C = 32*s8;  // L3
    const int k0H = 16*s8;                                  // G2 k-slice
    const int cG  = gA;                                     // G1 col
    const bool oct0  = (s8 == 0);
    const int rD = t>>3, j0D = (t&7)*8;                     // chunk roles

    // ---- F-weights -> scalar registers (zero-padded, 200 floats) ----
    float wf1a[20], wf1b[20];
#pragma unroll
    for (int k=0;k<20;++k){
        float wa=0.f, wb=0.f;
        if (k < lenA){
            wa = Wf1[(k0A+k)*HF + cA0];
            wb = Wf1[(k0A+k)*HF + cA0 + 1];
        }
        wf1a[k]=wa; wf1b[k]=wb;
    }
    float wf2s[32][4];
#pragma unroll
    for (int k=0;k<32;++k){
        const float4 wv = *(const float4*)&Wf2[(size_t)(k0B+k)*HF + cB0];
        wf2s[k][0]=wv.x; wf2s[k][1]=wv.y; wf2s[k][2]=wv.z; wf2s[k][3]=wv.w;
    }
    float wf3s[32];
#pragma unroll
    for (int k=0;k<32;++k) wf3s[k] = Wf3[(k0C+k)*NX + cC];

    const float2 bf1v = *(const float2*)&bf1[cA0];
    const float4 bf2v = *(const float4*)&bf2[cB0];
    const float bf3c = bf3[cC];
    const float bg1c = bg1[cG];
    const float bg2c = bg2[cC];

    // per-lane merged-tanh bias + write pointer (init-time selects only)
    float bf2sel = (s8&1) ? bf2v.y : bf2v.x;
    { const float tz = (s8&1) ? bf2v.w : bf2v.z; bf2sel = (s8&2) ? tz : bf2sel; }
    float* const pA_w = (q2==2) ? &s_hg[cG] : &s_h1[pmap(cA0) + (q2&1)];
    float* const pB_w = &s_h2[pmap(cB0) + (s8&3)];

    const float sq = sqrtf(DTC);
    const float* inB = gIn + (size_t)b*DIN*NT;
    const float* nzB = gNz + (size_t)b*NX*NT;
    float*      outB = gOut + (size_t)b*NX*NT;

    // ---- G-weights -> LDS; u sequence -> LDS; initial state ----
    // s_wg1p: [c][84], slice q at 20q..20q+19 holds Wg1[16q+r] (zero-padded)
    for (int i=t; i<HG*WG1P; i+=TPB){
        const int c = i/WG1P, j = i - c*WG1P;
        float v = 0.f;
        if (j < 80){
            const int q = j/20, r = j - q*20;
            if (r < ((q==3)?20:16)) v = Wg1[(16*q+r)*HG + c];
        }
        s_wg1p[i] = v;
    }
    for (int i=t;i<HG*NX;i+=TPB){
        const int k=i>>6, c=i&(NX-1);
        s_wg2t[c*WG2LD+k] = Wg2[i];
    }
    for (int i=t;i<NS*NT; i+=TPB) s_uall[i] = inB[(i&3)*NT + (i>>2)];
    if (t<8)            s_uall[NS*NT+t] = 0.f;
    if (t>=68 && t<72)  s_z[t] = 0.f;
    if (t<4)            s_z[64+t] = inB[t*NT];
    float X = inB[(size_t)(NS+cC)*NT];   // replicated across oct group
    float kacc = 0.f, gc = 0.f;
    if (oct0) s_z[cC] = X;
    __syncthreads();

    const float* const wgp = &s_wg1p[cG*WG1P + 20*q2];

    // ---------- phases ----------
    auto phaseA = [&](bool withG){
        float a0=0.f,a1=0.f,b0=0.f,b1=0.f,g0=0.f,g1=0.f;
#pragma unroll
        for (int q=0;q<5;++q){                 // weights zero-padded beyond lenA
            const float4 zv = *(const float4*)&s_z[k0A + 4*q];
            a0 = fmaf(zv.x, wf1a[4*q+0], a0);  b0 = fmaf(zv.x, wf1b[4*q+0], b0);
            a1 = fmaf(zv.y, wf1a[4*q+1], a1);  b1 = fmaf(zv.y, wf1b[4*q+1], b1);
            a0 = fmaf(zv.z, wf1a[4*q+2], a0);  b0 = fmaf(zv.z, wf1b[4*q+2], b0);
            a1 = fmaf(zv.w, wf1a[4*q+3], a1);  b1 = fmaf(zv.w, wf1b[4*q+3], b1);
            if (withG){
                const float4 wv = *(const float4*)&wgp[4*q];  // padded slice
                g0 = fmaf(zv.x, wv.x, g0);
                g1 = fmaf(zv.y, wv.y, g1);
                g0 = fmaf(zv.z, wv.z, g0);
                g1 = fmaf(zv.w, wv.w, g1);
            }
        }
        const float r0 = quad_sum(a0 + a1);
        const float r1 = quad_sum(b0 + b1);
        // merged tanh: one issue, per-lane input select + per-lane pointer
        float x = (q2==1) ? r1 + bf1v.y : r0 + bf1v.x;
        if (withG){
            const float gr = quad_sum(g0 + g1);
            x = (q2==2) ? gr + bg1c : x;
        }
        const float tv = tanh_fast(x);
        if (q2 < 3) *pA_w = tv;   // q2==2 lane: s_hg (garbage in ev1-3, unread)
        __syncthreads();
    };

    auto phaseB = [&](bool withG){
        float c0=0.f,c1=0.f,c2=0.f,c3=0.f;
        const float* h1p = &s_h1[36*s8];       // pmap(32*s8 + j) = 36*s8 + j
#pragma unroll
        for (int q=0;q<8;++q){
            const float4 hv = *(const float4*)&h1p[4*q];
            c0 = fmaf(hv.x, wf2s[4*q+0][0], c0);
            c1 = fmaf(hv.x, wf2s[4*q+0][1], c1);
            c2 = fmaf(hv.x, wf2s[4*q+0][2], c2);
            c3 = fmaf(hv.x, wf2s[4*q+0][3], c3);
            c0 = fmaf(hv.y, wf2s[4*q+1][0], c0);
            c1 = fmaf(hv.y, wf2s[4*q+1][1], c1);
            c2 = fmaf(hv.y, wf2s[4*q+1][2], c2);
            c3 = fmaf(hv.y, wf2s[4*q+1][3], c3);
            c0 = fmaf(hv.z, wf2s[4*q+2][0], c0);
            c1 = fmaf(hv.z, wf2s[4*q+2][1], c1);
            c2 = fmaf(hv.z, wf2s[4*q+2][2], c2);
            c3 = fmaf(hv.z, wf2s[4*q+2][3], c3);
            c0 = fmaf(hv.w, wf2s[4*q+3][0], c0);
            c1 = fmaf(hv.w, wf2s[4*q+3][1], c1);
            c2 = fmaf(hv.w, wf2s[4*q+3][2], c2);
            c3 = fmaf(hv.w, wf2s[4*q+3][3], c3);
        }
        const float d0 = oct_sum(c0);
        const float d1 = oct_sum(c1);
        const float d2 = oct_sum(c2);
        const float d3 = oct_sum(c3);
        if (withG){
            float g0=0.f, g1=0.f;
            const float* wt = &s_wg2t[cC*WG2LD + k0H];
            const float* hp = &s_hg[k0H];
#pragma unroll
            for (int q=0;q<4;++q){
                const float4 wv = *(const float4*)&wt[4*q];
                const float4 hg = *(const float4*)&hp[4*q];
                g0 = fmaf(hg.x, wv.x, g0);  g1 = fmaf(hg.y, wv.y, g1);
                g0 = fmaf(hg.z, wv.z, g0);  g1 = fmaf(hg.w, wv.w, g1);
            }
            const float gq = oct_sum(g0 + g1);
            gc = SIGMA*softplus_f(gq + bg2c);  // replicated across oct
        }
        // merged tanh: select d[s8&3], one issue, masked scalar write
        float xb = (s8&1) ? d1 : d0;
        { const float yb = (s8&1) ? d3 : d2; xb = (s8&2) ? yb : xb; }
        const float tv = tanh_fast(xb + bf2sel);
        if (s8 < 4) *pB_w = tv;
        __syncthreads();
    };

    auto phaseC = [&](int ev, int st){
        float e0=0.f, e1=0.f;
        const float* h2p = &s_h2[36*s8];
#pragma unroll
        for (int q=0;q<8;++q){
            const float4 hv = *(const float4*)&h2p[4*q];
            e0 = fmaf(hv.x, wf3s[4*q+0], e0);
            e1 = fmaf(hv.y, wf3s[4*q+1], e1);
            e0 = fmaf(hv.z, wf3s[4*q+2], e0);
            e1 = fmaf(hv.w, wf3s[4*q+3], e1);
        }
        const float kv = oct_sum(e0 + e1) + bf3c;      // replicated across oct
        if (ev==0)      kacc = kv;
        else if (ev==3) kacc += kv;
        else            kacc += 2.0f*kv;
        if (ev<3){
            if (oct0) s_z[cC] = fmaf((ev==2)?DTC:0.5f*DTC, kv, X);
        } else {
            const int jj = st & 63;
            const float dw = s_dwc[cC*CH + jj];        // broadcast within oct
            X = X + (DTC/6.0f)*kacc + gc*dw;           // replicated update
            if (oct0){
                s_z[cC] = X;
                s_out[cC*CH + jj] = X;
                if (cC < NS) s_z[64+cC] = s_uall[(st+1)*4 + cC];
            }
        }
        __syncthreads();
    };

    // ---------- main loop ----------
#pragma unroll 1
    for (int st=0; st<NT; ++st){
        // KEEPALIVE: opaquely redefine every F-weight register each step.
        // No instructions emitted; forbids sinking the weight loads back into
        // the loop (the r10 L2-refetch wall; removing this cost 2.8 ms).
#pragma unroll
        for (int k=0;k<20;++k)
            asm volatile("" : "+v"(wf1a[k]), "+v"(wf1b[k]));
#pragma unroll
        for (int k=0;k<32;++k)
            asm volatile("" : "+v"(wf2s[k][0]), "+v"(wf2s[k][1]),
                              "+v"(wf2s[k][2]), "+v"(wf2s[k][3]));
#pragma unroll
        for (int k=0;k<32;++k)
            asm volatile("" : "+v"(wf3s[k]));

        if ((st & 63) == 0){
            if (st + 64 <= NT){
                const float4 v0 = *(const float4*)&nzB[(size_t)rD*NT + st + j0D];
                const float4 v1 = *(const float4*)&nzB[(size_t)rD*NT + st + j0D + 4];
                float* d = &s_dwc[rD*CH + j0D];
                d[0]=v0.x*sq; d[1]=v0.y*sq; d[2]=v0.z*sq; d[3]=v0.w*sq;
                d[4]=v1.x*sq; d[5]=v1.y*sq; d[6]=v1.z*sq; d[7]=v1.w*sq;
            } else {
#pragma unroll
                for (int e=0;e<8;++e){
                    const int j = j0D + e;
                    const float v = (st + j < NT) ? nzB[(size_t)rD*NT + st + j] : 0.f;
                    s_dwc[rD*CH + j] = v*sq;
                }
            }
        }

        phaseA(true);  phaseB(true);  phaseC(0, st);
#pragma unroll
        for (int ev=1; ev<4; ++ev){
            phaseA(false); phaseB(false); phaseC(ev, st);
        }

        const int jj = st & 63;
        if (jj == 63 || st == NT-1){
            const int st0 = st & ~63;
            const int cnt = st - st0 + 1;
            if (cnt == 64){
                const float4 w0 = *(const float4*)&s_out[rD*CH + j0D];
                const float4 w1 = *(const float4*)&s_out[rD*CH + j0D + 4];
                *(float4*)&outB[(size_t)rD*NT + st0 + j0D]     = w0;
                *(float4*)&outB[(size_t)rD*NT + st0 + j0D + 4] = w1;
            } else {
#pragma unroll
                for (int e=0;e<8;++e){
                    const int j = j0D + e;
                    if (j < cnt) outB[(size_t)rD*NT + st0 + j] = s_out[rD*CH + j];
                }
            }
        }
    }
}

} // namespace

extern "C" void kernel_launch(void* const* d_in, const int* in_sizes, int n_in,
                              void* d_out, int out_size, void* d_ws, size_t ws_size,
                              hipStream_t stream)
{
    const float* Inputs = (const float*)d_in[0];
    const float* noise  = (const float*)d_in[1];
    // d_in[2] = t0 (unused)
    const float* Wf1 = (const float*)d_in[3];
    const float* bf1 = (const float*)d_in[4];
    const float* Wf2 = (const float*)d_in[5];
    const float* bf2 = (const float*)d_in[6];
    const float* Wf3 = (const float*)d_in[7];
    const float* bf3 = (const float*)d_in[8];
    const float* Wg1 = (const float*)d_in[9];
    const float* bg1 = (const float*)d_in[10];
    const float* Wg2 = (const float*)d_in[11];
    const float* bg2 = (const float*)d_in[12];
    float* out = (float*)d_out;

    sde_rk4_kernel<<<dim3(NB), dim3(TPB), 0, stream>>>(
        Inputs, noise, Wf1, bf1, Wf2, bf2, Wf3, bf3, Wg1, bg1, Wg2, bg2, out);
}